// Round 1
// baseline (134.171 us; speedup 1.0000x reference)
//
#include <hip/hip_runtime.h>

#define BB 16
#define NN 4096
#define CC 6
#define TJ 256            // j-tile staged in LDS
#define ICHUNK 512        // i-points per block (256 threads x 2)
#define JSPLIT 4          // j-range split across blocks, merged by atomicMin
#define JCHUNK (NN / JSPLIT)  // 1024

__global__ __launch_bounds__(256) void chamfer_min_kernel(
    const float* __restrict__ xg, const float* __restrict__ yg,
    unsigned int* __restrict__ ws)
{
    int bid = blockIdx.x;
    const int dir = bid & 1;            bid >>= 1;
    const int jsp = bid & (JSPLIT - 1); bid >>= 2;
    const int ic  = bid & 7;            bid >>= 3;
    const int b   = bid;                // 0..15

    const float* __restrict__ X = dir ? yg : xg;  // rows we take the min FOR
    const float* __restrict__ Y = dir ? xg : yg;  // points we min OVER
    unsigned int* __restrict__ mins = ws + (size_t)dir * BB * NN + (size_t)b * NN;

    const int tid = threadIdx.x;
    const int i0 = ic * ICHUNK + tid;
    const int i1 = i0 + 256;

    const size_t xb = (size_t)b * NN;
    const float x00 = X[(xb + i0) * CC + 0];
    const float x01 = X[(xb + i0) * CC + 1];
    const float x02 = X[(xb + i0) * CC + 2];
    const float x10 = X[(xb + i1) * CC + 0];
    const float x11 = X[(xb + i1) * CC + 1];
    const float x12 = X[(xb + i1) * CC + 2];
    const float rx0 = fmaf(x00, x00, fmaf(x01, x01, x02 * x02));
    const float rx1 = fmaf(x10, x10, fmaf(x11, x11, x12 * x12));

    __shared__ float4 ytile[TJ];

    float m0 = 3.4e38f, m1 = 3.4e38f;

    const int jbase0 = jsp * JCHUNK;
    for (int js = 0; js < JCHUNK; js += TJ) {
        const int j = jbase0 + js + tid;
        const float y0 = Y[(xb + j) * CC + 0];
        const float y1 = Y[(xb + j) * CC + 1];
        const float y2 = Y[(xb + j) * CC + 2];
        const float ry = fmaf(y0, y0, fmaf(y1, y1, y2 * y2));
        __syncthreads();   // previous tile fully consumed
        ytile[tid] = make_float4(-2.f * y0, -2.f * y1, -2.f * y2, ry);
        __syncthreads();

        #pragma unroll 8
        for (int jt = 0; jt < TJ; ++jt) {
            const float4 yv = ytile[jt];
            const float t0 = fmaf(x00, yv.x, fmaf(x01, yv.y, fmaf(x02, yv.z, yv.w)));
            const float t1 = fmaf(x10, yv.x, fmaf(x11, yv.y, fmaf(x12, yv.z, yv.w)));
            m0 = fminf(m0, t0);
            m1 = fminf(m1, t1);
        }
    }

    const float d0 = fmaxf(rx0 + m0, 0.0f);
    const float d1 = fmaxf(rx1 + m1, 0.0f);
    atomicMin(&mins[i0], __float_as_uint(d0));
    atomicMin(&mins[i1], __float_as_uint(d1));
}

__global__ __launch_bounds__(1024) void chamfer_reduce_kernel(
    const unsigned int* __restrict__ ws, float* __restrict__ out)
{
    const int TOT = 2 * BB * NN;  // 131072
    float s = 0.0f;
    for (int idx = threadIdx.x; idx < TOT; idx += 1024)
        s += __uint_as_float(ws[idx]);

    // wave-64 shuffle reduce
    for (int off = 32; off > 0; off >>= 1)
        s += __shfl_down(s, off, 64);

    __shared__ float wsum[16];
    const int wave = threadIdx.x >> 6;
    if ((threadIdx.x & 63) == 0) wsum[wave] = s;
    __syncthreads();
    if (threadIdx.x == 0) {
        float tot = 0.0f;
        #pragma unroll
        for (int w = 0; w < 16; ++w) tot += wsum[w];
        out[0] = tot * (1.0f / (BB * NN));
    }
}

extern "C" void kernel_launch(void* const* d_in, const int* in_sizes, int n_in,
                              void* d_out, int out_size, void* d_ws, size_t ws_size,
                              hipStream_t stream) {
    const float* x = (const float*)d_in[0];
    const float* y = (const float*)d_in[1];
    float* out = (float*)d_out;
    unsigned int* ws = (unsigned int*)d_ws;

    // init mins to +max (uint-ordered); 2*B*N floats = 512 KiB
    hipMemsetAsync(d_ws, 0xFF, (size_t)2 * BB * NN * sizeof(unsigned int), stream);

    const int nblocks = 2 * BB * (NN / ICHUNK) * JSPLIT;  // 1024
    chamfer_min_kernel<<<nblocks, 256, 0, stream>>>(x, y, ws);
    chamfer_reduce_kernel<<<1, 1024, 0, stream>>>(ws, out);
}

// Round 2
// 105.786 us; speedup vs baseline: 1.2683x; 1.2683x over previous
//
#include <hip/hip_runtime.h>

#define BB 16
#define NN 4096
#define CC 6
#define TJ 256                 // j-tile staged in LDS
#define JSPLIT 4               // j-range split across blocks, merged in reduce
#define JCHUNK (NN / JSPLIT)   // 1024
#define IPT 4                  // i-points per thread (4 independent dep chains)
#define ICHUNK (256 * IPT)     // 1024
#define NSEG (BB * NN)         // 65536 rows per direction

// grid = dir(2) x jsp(4) x ic(4) x b(16) = 512 blocks, 256 threads
__global__ __launch_bounds__(256) void chamfer_min_kernel(
    const float* __restrict__ xg, const float* __restrict__ yg,
    float* __restrict__ ws)
{
    int bid = blockIdx.x;
    const int dir = bid & 1;
    const int jsp = (bid >> 1) & (JSPLIT - 1);
    const int ic  = (bid >> 3) & 3;
    const int b   = bid >> 5;

    const float* __restrict__ X = dir ? yg : xg;  // rows we take the min FOR
    const float* __restrict__ Y = dir ? xg : yg;  // points we min OVER

    const int tid = threadIdx.x;
    const size_t xb = (size_t)b * NN;

    float x0[IPT], x1[IPT], x2[IPT], rx[IPT], m[IPT];
    #pragma unroll
    for (int r = 0; r < IPT; ++r) {
        const int i = ic * ICHUNK + r * 256 + tid;
        x0[r] = X[(xb + i) * CC + 0];
        x1[r] = X[(xb + i) * CC + 1];
        x2[r] = X[(xb + i) * CC + 2];
        rx[r] = fmaf(x0[r], x0[r], fmaf(x1[r], x1[r], x2[r] * x2[r]));
        m[r]  = 3.4e38f;
    }

    __shared__ float4 ytile[TJ];

    const int jbase0 = jsp * JCHUNK;
    for (int js = 0; js < JCHUNK; js += TJ) {
        const int j = jbase0 + js + tid;
        const float y0 = Y[(xb + j) * CC + 0];
        const float y1 = Y[(xb + j) * CC + 1];
        const float y2 = Y[(xb + j) * CC + 2];
        const float ry = fmaf(y0, y0, fmaf(y1, y1, y2 * y2));
        __syncthreads();   // previous tile fully consumed
        ytile[tid] = make_float4(-2.f * y0, -2.f * y1, -2.f * y2, ry);
        __syncthreads();

        #pragma unroll 4
        for (int jt = 0; jt < TJ; jt += 2) {
            const float4 va = ytile[jt];
            const float4 vb = ytile[jt + 1];
            #pragma unroll
            for (int r = 0; r < IPT; ++r) {
                const float ta = fmaf(x0[r], va.x, fmaf(x1[r], va.y, fmaf(x2[r], va.z, va.w)));
                const float tb = fmaf(x0[r], vb.x, fmaf(x1[r], vb.y, fmaf(x2[r], vb.z, vb.w)));
                m[r] = fminf(m[r], fminf(ta, tb));   // -> v_min3_f32
            }
        }
    }

    // plain stores of partial (per-jsplit) row results; no atomics
    float* __restrict__ dst = ws + ((size_t)(dir * JSPLIT + jsp) * BB + b) * NN;
    #pragma unroll
    for (int r = 0; r < IPT; ++r) {
        const int i = ic * ICHUNK + r * 256 + tid;
        dst[i] = rx[r] + m[r];
    }
}

// 128 blocks x 256 threads: min over JSPLIT partials, sum, one atomicAdd/block
__global__ __launch_bounds__(256) void chamfer_reduce_kernel(
    const float* __restrict__ ws, float* __restrict__ out)
{
    const int PTS = 2 * NSEG;  // 131072
    float s = 0.0f;
    for (int p = blockIdx.x * 256 + threadIdx.x; p < PTS; p += gridDim.x * 256) {
        const int dir = p >> 16;          // p / NSEG
        const int rem = p & (NSEG - 1);   // p % NSEG
        const float* base = ws + (size_t)dir * JSPLIT * NSEG + rem;
        float v = base[0];
        #pragma unroll
        for (int sg = 1; sg < JSPLIT; ++sg)
            v = fminf(v, base[(size_t)sg * NSEG]);
        s += v;
    }

    for (int off = 32; off > 0; off >>= 1)
        s += __shfl_down(s, off, 64);

    __shared__ float wsum[4];
    const int wave = threadIdx.x >> 6;
    if ((threadIdx.x & 63) == 0) wsum[wave] = s;
    __syncthreads();
    if (threadIdx.x == 0) {
        const float tot = wsum[0] + wsum[1] + wsum[2] + wsum[3];
        atomicAdd(out, tot * (1.0f / NSEG));
    }
}

extern "C" void kernel_launch(void* const* d_in, const int* in_sizes, int n_in,
                              void* d_out, int out_size, void* d_ws, size_t ws_size,
                              hipStream_t stream) {
    const float* x = (const float*)d_in[0];
    const float* y = (const float*)d_in[1];
    float* out = (float*)d_out;
    float* ws = (float*)d_ws;

    hipMemsetAsync(d_out, 0, sizeof(float), stream);  // out accumulates via atomicAdd

    const int nblocks = 2 * JSPLIT * (NN / ICHUNK) * BB;  // 512
    chamfer_min_kernel<<<nblocks, 256, 0, stream>>>(x, y, ws);
    chamfer_reduce_kernel<<<128, 256, 0, stream>>>(ws, out);
}